// Round 24
// baseline (114.362 us; speedup 1.0000x reference)
//
#include <hip/hip_runtime.h>

// ---------------- fixed problem shape ----------------
#define BATCH  2
#define SEQ    2048
#define DMODEL 1024
#define NHEAD  16
#define HDIM   64
#define NROWS  (BATCH * SEQ)   // 4096
#define QKVC   (3 * DMODEL)    // 3072

typedef float f32x4 __attribute__((ext_vector_type(4)));
typedef float f32x16 __attribute__((ext_vector_type(16)));
typedef short s16x8 __attribute__((ext_vector_type(8)));
typedef short s16x4 __attribute__((ext_vector_type(4)));
typedef unsigned int u32x4 __attribute__((ext_vector_type(4)));

__device__ __forceinline__ unsigned short f2bf(float f) {
  unsigned int u = __float_as_uint(f);
  u = (u + 0x7FFFu + ((u >> 16) & 1u)) >> 16;   // RNE
  return (unsigned short)u;
}
__device__ __forceinline__ float bf2f(unsigned short s) {
  return __uint_as_float(((unsigned int)s) << 16);
}
__device__ __forceinline__ unsigned pkbf(float a, float b) {
  unsigned r;
  asm("v_cvt_pk_bf16_f32 %0, %1, %2" : "=v"(r) : "v"(a), "v"(b));
  return r;
}
// v_permlane32_swap_b32 DST, SRC: DST[32:63] <-> SRC[0:31]
// SAFE only with two genuinely distinct values (R7 lesson).
__device__ __forceinline__ void swp(unsigned &a, unsigned &b) {
  asm volatile("v_permlane32_swap_b32 %0, %1" : "+v"(a), "+v"(b));
}

// ---------------------------------------------------------------------------
// 1) MERGED prep kernel (R21 champion, byte-identical)
// ---------------------------------------------------------------------------
__global__ __launch_bounds__(256) void k_prep(const float* __restrict__ Wq_src,
                                              const float* __restrict__ Wo_src,
                                              const float* __restrict__ X,
                                              unsigned short* __restrict__ Wq,
                                              unsigned short* __restrict__ Wo,
                                              unsigned short* __restrict__ Xb) {
  const int row = blockIdx.x, tid = threadIdx.x;
  if (row < QKVC + DMODEL) {
    const float* src = (row < QKVC) ? (Wq_src + (size_t)row * DMODEL)
                                    : (Wo_src + (size_t)(row - QKVC) * DMODEL);
    unsigned short* dst = (row < QKVC) ? (Wq + (size_t)row * DMODEL)
                                       : (Wo + (size_t)(row - QKVC) * DMODEL);
    float4 v = ((const float4*)src)[tid];
    float ss = v.x * v.x + v.y * v.y + v.z * v.z + v.w * v.w;
#pragma unroll
    for (int m = 1; m < 64; m <<= 1) ss += __shfl_xor(ss, m);
    __shared__ float part[4];
    if ((tid & 63) == 0) part[tid >> 6] = ss;
    __syncthreads();
    const float tot = part[0] + part[1] + part[2] + part[3];
    const float scale = 0.03125f / (1e-4f + sqrtf(tot) * 0.03125f);
    unsigned short* op = dst + tid * 4;
    op[0] = f2bf(v.x * scale); op[1] = f2bf(v.y * scale);
    op[2] = f2bf(v.z * scale); op[3] = f2bf(v.w * scale);
  } else {
    const int r = row - (QKVC + DMODEL);
    const float4 v = ((const float4*)(X + (size_t)r * DMODEL))[tid];
    ushort4 o = { f2bf(v.x), f2bf(v.y), f2bf(v.z), f2bf(v.w) };
    ((ushort4*)(Xb + (size_t)r * DMODEL))[tid] = o;
  }
}

// ---------------------------------------------------------------------------
// 2a) QKV GEMM — R24: 8-wave re-tile of the champion. Same 128x128 block
//     tile, grid, staging bytes, fused epilogues; wave sub-tile 32x64
//     (acc[2][4]) -> ~half VGPR, launch_bounds(512,4) -> 16 waves/CU
//     (was 12), compute phases half as long for finer barrier interleave.
//     Wave col-slab stays 64-wide so qk-norm/V-transpose carry over (m<2).
// ---------------------------------------------------------------------------
#define LDP 88
__global__ __launch_bounds__(512, 4) void k_gemm_qkv(const unsigned short* __restrict__ A,
                                                     const unsigned short* __restrict__ Bm,
                                                     unsigned short* __restrict__ C,
                                                     unsigned short* __restrict__ Vt) {
  const int M = NROWS, N = QKVC, K = DMODEL;
  __shared__ unsigned short As[128 * LDP];
  __shared__ unsigned short Bs[128 * LDP];
  const int tid = threadIdx.x;
  const int nbn = N >> 7;
  const int bm = (blockIdx.x / nbn) << 7;
  const int bn = (blockIdx.x % nbn) << 7;
  const int wave = tid >> 6, lane = tid & 63;
  const int wr = (wave >> 1) << 5;     // 4 row-groups x 32 rows
  const int wc = (wave & 1) << 6;      // 2 col-groups x 64 cols
  const int l16 = lane & 15, lg = lane >> 4;

  f32x4 acc[2][4];
#pragma unroll
  for (int m = 0; m < 2; ++m)
#pragma unroll
    for (int n = 0; n < 4; ++n) acc[m][n] = (f32x4){0.f, 0.f, 0.f, 0.f};

  s16x8 ra[2], rb[2];
#pragma unroll
  for (int it = 0; it < 2; ++it) {
    const int c = it * 512 + tid;
    const int r = c >> 3, col = (c & 7) << 3;
    ra[it] = *(const s16x8*)(A + (size_t)(bm + r) * K + col);
    rb[it] = *(const s16x8*)(Bm + (size_t)(bn + r) * K + col);
  }

  for (int k0 = 0; k0 < K; k0 += 64) {
    __syncthreads();   // A: previous tile fully consumed
#pragma unroll
    for (int it = 0; it < 2; ++it) {
      const int c = it * 512 + tid;
      const int r = c >> 3, col = (c & 7) << 3;
      *(s16x8*)(As + r * LDP + col) = ra[it];
      *(s16x8*)(Bs + r * LDP + col) = rb[it];
    }
    __syncthreads();   // B: staged tile visible
    if (k0 + 64 < K) { // EARLY ISSUE (R14): next tile loads overlap compute
#pragma unroll
      for (int it = 0; it < 2; ++it) {
        const int c = it * 512 + tid;
        const int r = c >> 3, col = (c & 7) << 3;
        ra[it] = *(const s16x8*)(A + (size_t)(bm + r) * K + k0 + 64 + col);
        rb[it] = *(const s16x8*)(Bm + (size_t)(bn + r) * K + k0 + 64 + col);
      }
    }
#pragma unroll
    for (int ks = 0; ks < 2; ++ks) {
      s16x8 af[2], bq[4];
#pragma unroll
      for (int m = 0; m < 2; ++m)
        af[m] = *(const s16x8*)(As + (wr + m * 16 + l16) * LDP + ks * 32 + lg * 8);
#pragma unroll
      for (int n = 0; n < 4; ++n)
        bq[n] = *(const s16x8*)(Bs + (wc + n * 16 + l16) * LDP + ks * 32 + lg * 8);
#pragma unroll
      for (int m = 0; m < 2; ++m)
#pragma unroll
        for (int n = 0; n < 4; ++n)
          acc[m][n] = __builtin_amdgcn_mfma_f32_16x16x32_bf16(af[m], bq[n], acc[m][n], 0, 0, 0);
    }
  }

  const int colbase = bn + wc;   // 64-aligned -> exactly one head-dim slab
  if (colbase < 2 * DMODEL) {
    // q/k: fused EDM2 norm (+1/8 attn scale for q), write bf16
    const float qmul = (colbase < DMODEL) ? 0.125f : 1.0f;
#pragma unroll
    for (int m = 0; m < 2; ++m)
#pragma unroll
      for (int r = 0; r < 4; ++r) {
        float ss = 0.f;
#pragma unroll
        for (int n = 0; n < 4; ++n) ss += acc[m][n][r] * acc[m][n][r];
        ss += __shfl_xor(ss, 1); ss += __shfl_xor(ss, 2);
        ss += __shfl_xor(ss, 4); ss += __shfl_xor(ss, 8);
        const float scale = qmul / (1e-4f + sqrtf(ss) * 0.125f);
#pragma unroll
        for (int n = 0; n < 4; ++n)
          C[(size_t)(bm + wr + m * 16 + lg * 4 + r) * N + (colbase + n * 16 + l16)] =
              f2bf(acc[m][n][r] * scale);
      }
  } else {
    // v: write transposed to Vt[bh][d][t]
    const int hv = (colbase - 2 * DMODEL) >> 6;
    const int token0 = bm + wr;
    const int b_ = token0 >> 11;
    const int bh = b_ * NHEAD + hv;
    const int t0 = (token0 & (SEQ - 1)) + lg * 4;
#pragma unroll
    for (int m = 0; m < 2; ++m)
#pragma unroll
      for (int n = 0; n < 4; ++n) {
        const int d = n * 16 + l16;
        s16x4 ov = { (short)f2bf(acc[m][n][0]), (short)f2bf(acc[m][n][1]),
                     (short)f2bf(acc[m][n][2]), (short)f2bf(acc[m][n][3]) };
        *(s16x4*)(Vt + (size_t)(bh * HDIM + d) * SEQ + t0 + m * 16) = ov;
      }
  }
}

// ---------------------------------------------------------------------------
// 2b) out GEMM — R14/R16 winner, f32 output (unchanged control)
// ---------------------------------------------------------------------------
__global__ __launch_bounds__(256, 3) void k_gemm_out(const unsigned short* __restrict__ A,
                                                     const unsigned short* __restrict__ Bm,
                                                     float* __restrict__ C,
                                                     int M, int N, int K) {
  __shared__ unsigned short As[128 * LDP];
  __shared__ unsigned short Bs[128 * LDP];
  const int tid = threadIdx.x;
  const int nbn = N >> 7;
  const int bm = (blockIdx.x / nbn) << 7;
  const int bn = (blockIdx.x % nbn) << 7;
  const int wave = tid >> 6, lane = tid & 63;
  const int wr = (wave >> 1) << 6, wc = (wave & 1) << 6;
  const int l16 = lane & 15, lg = lane >> 4;

  f32x4 acc[4][4];
#pragma unroll
  for (int m = 0; m < 4; ++m)
#pragma unroll
    for (int n = 0; n < 4; ++n) acc[m][n] = (f32x4){0.f, 0.f, 0.f, 0.f};

  s16x8 ra[4], rb[4];
#pragma unroll
  for (int it = 0; it < 4; ++it) {
    const int c = it * 256 + tid;
    const int r = c >> 3, col = (c & 7) << 3;
    ra[it] = *(const s16x8*)(A + (size_t)(bm + r) * K + col);
    rb[it] = *(const s16x8*)(Bm + (size_t)(bn + r) * K + col);
  }

  for (int k0 = 0; k0 < K; k0 += 64) {
    __syncthreads();
#pragma unroll
    for (int it = 0; it < 4; ++it) {
      const int c = it * 256 + tid;
      const int r = c >> 3, col = (c & 7) << 3;
      *(s16x8*)(As + r * LDP + col) = ra[it];
      *(s16x8*)(Bs + r * LDP + col) = rb[it];
    }
    __syncthreads();
    if (k0 + 64 < K) {
#pragma unroll
      for (int it = 0; it < 4; ++it) {
        const int c = it * 256 + tid;
        const int r = c >> 3, col = (c & 7) << 3;
        ra[it] = *(const s16x8*)(A + (size_t)(bm + r) * K + k0 + 64 + col);
        rb[it] = *(const s16x8*)(Bm + (size_t)(bn + r) * K + k0 + 64 + col);
      }
    }
#pragma unroll
    for (int ks = 0; ks < 2; ++ks) {
      s16x8 af[4], bq[4];
#pragma unroll
      for (int m = 0; m < 4; ++m)
        af[m] = *(const s16x8*)(As + (wr + m * 16 + l16) * LDP + ks * 32 + lg * 8);
#pragma unroll
      for (int n = 0; n < 4; ++n)
        bq[n] = *(const s16x8*)(Bs + (wc + n * 16 + l16) * LDP + ks * 32 + lg * 8);
#pragma unroll
      for (int m = 0; m < 4; ++m)
#pragma unroll
        for (int n = 0; n < 4; ++n)
          acc[m][n] = __builtin_amdgcn_mfma_f32_16x16x32_bf16(af[m], bq[n], acc[m][n], 0, 0, 0);
    }
  }
#pragma unroll
  for (int m = 0; m < 4; ++m)
#pragma unroll
    for (int n = 0; n < 4; ++n)
#pragma unroll
      for (int r = 0; r < 4; ++r)
        C[(size_t)(bm + wr + m * 16 + lg * 4 + r) * N + (bn + wc + n * 16 + l16)] =
            acc[m][n][r];
}

// ---------------------------------------------------------------------------
// 3) flash attention — R15/R16 CHAMPION, byte-identical.
// ---------------------------------------------------------------------------
__global__ __launch_bounds__(512) void k_attn(const unsigned short* __restrict__ qkv,
                                              const unsigned short* __restrict__ Vt,
                                              unsigned short* __restrict__ O) {
  const int bid = blockIdx.x;
  const int logical = ((bid & 7) << 6) + (bid >> 3);   // XCD clustering (512%8==0)
  const int bh = logical >> 4, qt = logical & 15;
  const int b = bh >> 4, h = bh & 15;
  const int tid = threadIdx.x;
  const int wave = tid >> 6, lane = tid & 63;
  const int l31 = lane & 31, hi = lane >> 5;
  const int qw = wave & 3, half = wave >> 2;
  const int q0 = qt * 128 + qw * 32;

  __shared__ s16x8 smem[2048];   // [half][K 512 | V 512] staging (32KB); merge alias
  __shared__ float LL[4][64];

  s16x8* ksh = smem + half * 512;
  s16x8* vsh = smem + 1024 + half * 512;

  const unsigned short* qp =
      qkv + (size_t)(b * SEQ + q0 + l31) * QKVC + h * HDIM + hi * 8;
  const s16x8 qf0 = *(const s16x8*)(qp);
  const s16x8 qf1 = *(const s16x8*)(qp + 16);
  const s16x8 qf2 = *(const s16x8*)(qp + 32);
  const s16x8 qf3 = *(const s16x8*)(qp + 48);

  const int t8 = tid & 255;
  const int srow = t8 >> 3, chunk = t8 & 7;
  const unsigned short* ksrc =
      qkv + (size_t)(b * SEQ + half * 1024 + srow) * QKVC + DMODEL + h * HDIM + chunk * 8;
  const unsigned short* vsrc =
      Vt + (size_t)(bh * HDIM + srow) * SEQ + half * 1024 + chunk * 8;
  const int wsl = srow * 8 + (chunk ^ (srow & 7));
  const int wsh = wsl + 256;

  f32x16 acc0 = {0,0,0,0,0,0,0,0,0,0,0,0,0,0,0,0};
  f32x16 acc1 = {0,0,0,0,0,0,0,0,0,0,0,0,0,0,0,0};
  float l = 0.f;

  for (int kt = 0; kt < 1024; kt += 64) {
    const s16x8 rk0 = *(const s16x8*)(ksrc + (size_t)kt * QKVC);
    const s16x8 rk1 = *(const s16x8*)(ksrc + (size_t)(kt + 32) * QKVC);
    const s16x8 rv0 = *(const s16x8*)(vsrc + kt);
    const s16x8 rv1 = *(const s16x8*)(vsrc + (size_t)32 * SEQ + kt);
    __syncthreads();
    ksh[wsl] = rk0; ksh[wsh] = rk1;
    vsh[wsl] = rv0; vsh[wsh] = rv1;
    __syncthreads();
#pragma unroll
    for (int kh = 0; kh < 2; ++kh) {
      const int key = kh * 32 + l31;
      const int kb = key * 8, kx = key & 7;
      f32x16 st = {0,0,0,0,0,0,0,0,0,0,0,0,0,0,0,0};
      st = __builtin_amdgcn_mfma_f32_32x32x16_bf16(ksh[kb + ((0 + hi) ^ kx)], qf0, st, 0, 0, 0);
      st = __builtin_amdgcn_mfma_f32_32x32x16_bf16(ksh[kb + ((2 + hi) ^ kx)], qf1, st, 0, 0, 0);
      st = __builtin_amdgcn_mfma_f32_32x32x16_bf16(ksh[kb + ((4 + hi) ^ kx)], qf2, st, 0, 0, 0);
      st = __builtin_amdgcn_mfma_f32_32x32x16_bf16(ksh[kb + ((6 + hi) ^ kx)], qf3, st, 0, 0, 0);

#pragma unroll
      for (int r = 0; r < 16; ++r) st[r] = __expf(st[r] - 8.f);

      float s0 = (st[0] + st[1]) + (st[2] + st[3]);
      float s1 = (st[4] + st[5]) + (st[6] + st[7]);
      float s2 = (st[8] + st[9]) + (st[10] + st[11]);
      float s3 = (st[12] + st[13]) + (st[14] + st[15]);
      l += (s0 + s1) + (s2 + s3);

      unsigned P0 = pkbf(st[0], st[1]),   P1 = pkbf(st[2], st[3]);
      unsigned P2 = pkbf(st[4], st[5]),   P3 = pkbf(st[6], st[7]);
      unsigned P4 = pkbf(st[8], st[9]),   P5 = pkbf(st[10], st[11]);
      unsigned P6 = pkbf(st[12], st[13]), P7 = pkbf(st[14], st[15]);
      swp(P0, P2);
      swp(P1, P3);
      swp(P4, P6);
      swp(P5, P7);
      u32x4 w0; w0[0] = P0; w0[1] = P1; w0[2] = P2; w0[3] = P3;
      u32x4 w1; w1[0] = P4; w1[1] = P5; w1[2] = P6; w1[3] = P7;
      const s16x8 pf0 = __builtin_bit_cast(s16x8, w0);
      const s16x8 pf1 = __builtin_bit_cast(s16x8, w1);

      const int vb0 = l31 * 8,        vx0 = l31 & 7;
      const int vb1 = (l31 + 32) * 8, vx1 = vx0;
      acc0 = __builtin_amdgcn_mfma_f32_32x32x16_bf16(vsh[vb0 + ((kh * 4 + 0 + hi) ^ vx0)], pf0, acc0, 0, 0, 0);
      acc0 = __builtin_amdgcn_mfma_f32_32x32x16_bf16(vsh[vb0 + ((kh * 4 + 2 + hi) ^ vx0)], pf1, acc0, 0, 0, 0);
      acc1 = __builtin_amdgcn_mfma_f32_32x32x16_bf16(vsh[vb1 + ((kh * 4 + 0 + hi) ^ vx1)], pf0, acc1, 0, 0, 0);
      acc1 = __builtin_amdgcn_mfma_f32_32x32x16_bf16(vsh[vb1 + ((kh * 4 + 2 + hi) ^ vx1)], pf1, acc1, 0, 0, 0);
    }
  }

  l += __shfl_xor(l, 32);

  __syncthreads();
  float* OO = (float*)smem;
  if (half) {
    float* o_ = OO + qw * 2048;
#pragma unroll
    for (int r = 0; r < 16; ++r) {
      o_[r * 64 + lane] = acc0[r];
      o_[(16 + r) * 64 + lane] = acc1[r];
    }
    LL[qw][lane] = l;
  }
  __syncthreads();
  if (!half) {
    const float inv = 1.f / (l + LL[qw][lane]);
    const float* o_ = OO + qw * 2048;
    unsigned short* ob = O + (size_t)(b * SEQ + q0 + l31) * DMODEL + h * HDIM;
#pragma unroll
    for (int g = 0; g < 4; ++g) {
      float e00 = (acc0[4 * g]     + o_[(4 * g) * 64 + lane])     * inv;
      float e01 = (acc0[4 * g + 1] + o_[(4 * g + 1) * 64 + lane]) * inv;
      float e02 = (acc0[4 * g + 2] + o_[(4 * g + 2) * 64 + lane]) * inv;
      float e03 = (acc0[4 * g + 3] + o_[(4 * g + 3) * 64 + lane]) * inv;
      float e10 = (acc1[4 * g]     + o_[(16 + 4 * g) * 64 + lane])     * inv;
      float e11 = (acc1[4 * g + 1] + o_[(16 + 4 * g + 1) * 64 + lane]) * inv;
      float e12 = (acc1[4 * g + 2] + o_[(16 + 4 * g + 2) * 64 + lane]) * inv;
      float e13 = (acc1[4 * g + 3] + o_[(16 + 4 * g + 3) * 64 + lane]) * inv;
      s16x4 o0 = { (short)f2bf(e00), (short)f2bf(e01), (short)f2bf(e02), (short)f2bf(e03) };
      s16x4 o1 = { (short)f2bf(e10), (short)f2bf(e11), (short)f2bf(e12), (short)f2bf(e13) };
      *(s16x4*)(ob + g * 8 + hi * 4) = o0;
      *(s16x4*)(ob + 32 + g * 8 + hi * 4) = o1;
    }
  }
}

// ---------------------------------------------------------------------------
// launch: ws layout (bytes): Wq[0,6M) Wo[6M,8M) Xb[8M,16M) QKV[16M,40M) Vt[40M,48M)
// ---------------------------------------------------------------------------
extern "C" void kernel_launch(void* const* d_in, const int* in_sizes, int n_in,
                              void* d_out, int out_size, void* d_ws, size_t ws_size,
                              hipStream_t stream) {
  const float* x    = (const float*)d_in[0];
  const float* wqkv = (const float*)d_in[1];
  const float* wout = (const float*)d_in[2];
  char* ws = (char*)d_ws;
  unsigned short* Wq  = (unsigned short*)(ws);
  unsigned short* Wo  = (unsigned short*)(ws + 6291456);
  unsigned short* Xb  = (unsigned short*)(ws + 8388608);
  unsigned short* QKV = (unsigned short*)(ws + 16777216);
  unsigned short* Vt  = (unsigned short*)(ws + 41943040);
  (void)in_sizes; (void)n_in; (void)out_size; (void)ws_size;

  k_prep<<<QKVC + DMODEL + NROWS, 256, 0, stream>>>(wqkv, wout, x, Wq, Wo, Xb);
  k_gemm_qkv<<<(NROWS / 128) * (QKVC / 128), 512, 0, stream>>>(Xb, Wq, QKV, Vt);
  k_attn<<<BATCH * NHEAD * 16, 512, 0, stream>>>(QKV, Vt, Xb);
  k_gemm_out<<<(NROWS / 128) * (DMODEL / 128), 256, 0, stream>>>(
      Xb, Wo, (float*)d_out, NROWS, DMODEL, DMODEL);
}

// Round 25
// 113.500 us; speedup vs baseline: 1.0076x; 1.0076x over previous
//
#include <hip/hip_runtime.h>

// ---------------- fixed problem shape ----------------
#define BATCH  2
#define SEQ    2048
#define DMODEL 1024
#define NHEAD  16
#define HDIM   64
#define NROWS  (BATCH * SEQ)   // 4096
#define QKVC   (3 * DMODEL)    // 3072

typedef float f32x4 __attribute__((ext_vector_type(4)));
typedef float f32x16 __attribute__((ext_vector_type(16)));
typedef short s16x8 __attribute__((ext_vector_type(8)));
typedef short s16x4 __attribute__((ext_vector_type(4)));
typedef unsigned int u32x4 __attribute__((ext_vector_type(4)));

__device__ __forceinline__ unsigned short f2bf(float f) {
  unsigned int u = __float_as_uint(f);
  u = (u + 0x7FFFu + ((u >> 16) & 1u)) >> 16;   // RNE
  return (unsigned short)u;
}
__device__ __forceinline__ float bf2f(unsigned short s) {
  return __uint_as_float(((unsigned int)s) << 16);
}
__device__ __forceinline__ unsigned pkbf(float a, float b) {
  unsigned r;
  asm("v_cvt_pk_bf16_f32 %0, %1, %2" : "=v"(r) : "v"(a), "v"(b));
  return r;
}
// v_permlane32_swap_b32 DST, SRC: DST[32:63] <-> SRC[0:31]
// SAFE only with two genuinely distinct values (R7 lesson).
__device__ __forceinline__ void swp(unsigned &a, unsigned &b) {
  asm volatile("v_permlane32_swap_b32 %0, %1" : "+v"(a), "+v"(b));
}

// ---------------------------------------------------------------------------
// 1) MERGED prep kernel: rows [0,4096) = weight-row-normalize (wqkv|wout),
//    rows [4096,8192) = plain f32->bf16 cast of x. Block-uniform branch.
// ---------------------------------------------------------------------------
__global__ __launch_bounds__(256) void k_prep(const float* __restrict__ Wq_src,
                                              const float* __restrict__ Wo_src,
                                              const float* __restrict__ X,
                                              unsigned short* __restrict__ Wq,
                                              unsigned short* __restrict__ Wo,
                                              unsigned short* __restrict__ Xb) {
  const int row = blockIdx.x, tid = threadIdx.x;
  if (row < QKVC + DMODEL) {
    const float* src = (row < QKVC) ? (Wq_src + (size_t)row * DMODEL)
                                    : (Wo_src + (size_t)(row - QKVC) * DMODEL);
    unsigned short* dst = (row < QKVC) ? (Wq + (size_t)row * DMODEL)
                                       : (Wo + (size_t)(row - QKVC) * DMODEL);
    float4 v = ((const float4*)src)[tid];
    float ss = v.x * v.x + v.y * v.y + v.z * v.z + v.w * v.w;
#pragma unroll
    for (int m = 1; m < 64; m <<= 1) ss += __shfl_xor(ss, m);
    __shared__ float part[4];
    if ((tid & 63) == 0) part[tid >> 6] = ss;
    __syncthreads();
    const float tot = part[0] + part[1] + part[2] + part[3];
    const float scale = 0.03125f / (1e-4f + sqrtf(tot) * 0.03125f);
    unsigned short* op = dst + tid * 4;
    op[0] = f2bf(v.x * scale); op[1] = f2bf(v.y * scale);
    op[2] = f2bf(v.z * scale); op[3] = f2bf(v.w * scale);
  } else {
    const int r = row - (QKVC + DMODEL);
    const float4 v = ((const float4*)(X + (size_t)r * DMODEL))[tid];
    ushort4 o = { f2bf(v.x), f2bf(v.y), f2bf(v.z), f2bf(v.w) };
    ((ushort4*)(Xb + (size_t)r * DMODEL))[tid] = o;
  }
}

// ---------------------------------------------------------------------------
// 2a) QKV GEMM, fused qk-norm + V-transpose (R16 champion)
// ---------------------------------------------------------------------------
#define LDP 88
__global__ __launch_bounds__(256, 3) void k_gemm_qkv(const unsigned short* __restrict__ A,
                                                     const unsigned short* __restrict__ Bm,
                                                     unsigned short* __restrict__ C,
                                                     unsigned short* __restrict__ Vt) {
  const int M = NROWS, N = QKVC, K = DMODEL;
  __shared__ unsigned short As[128 * LDP];
  __shared__ unsigned short Bs[128 * LDP];
  const int tid = threadIdx.x;
  const int nbn = N >> 7;
  const int bm = (blockIdx.x / nbn) << 7;
  const int bn = (blockIdx.x % nbn) << 7;
  const int wave = tid >> 6, lane = tid & 63;
  const int wr = (wave >> 1) << 6, wc = (wave & 1) << 6;
  const int l16 = lane & 15, lg = lane >> 4;

  f32x4 acc[4][4];
#pragma unroll
  for (int m = 0; m < 4; ++m)
#pragma unroll
    for (int n = 0; n < 4; ++n) acc[m][n] = (f32x4){0.f, 0.f, 0.f, 0.f};

  s16x8 ra[4], rb[4];
#pragma unroll
  for (int it = 0; it < 4; ++it) {
    const int c = it * 256 + tid;
    const int r = c >> 3, col = (c & 7) << 3;
    ra[it] = *(const s16x8*)(A + (size_t)(bm + r) * K + col);
    rb[it] = *(const s16x8*)(Bm + (size_t)(bn + r) * K + col);
  }

  for (int k0 = 0; k0 < K; k0 += 64) {
    __syncthreads();   // A: previous tile fully consumed
#pragma unroll
    for (int it = 0; it < 4; ++it) {
      const int c = it * 256 + tid;
      const int r = c >> 3, col = (c & 7) << 3;
      *(s16x8*)(As + r * LDP + col) = ra[it];
      *(s16x8*)(Bs + r * LDP + col) = rb[it];
    }
    __syncthreads();   // B: staged tile visible
    if (k0 + 64 < K) { // EARLY ISSUE: next tile loads overlap compute below
#pragma unroll
      for (int it = 0; it < 4; ++it) {
        const int c = it * 256 + tid;
        const int r = c >> 3, col = (c & 7) << 3;
        ra[it] = *(const s16x8*)(A + (size_t)(bm + r) * K + k0 + 64 + col);
        rb[it] = *(const s16x8*)(Bm + (size_t)(bn + r) * K + k0 + 64 + col);
      }
    }
#pragma unroll
    for (int ks = 0; ks < 2; ++ks) {
      s16x8 af[4], bq[4];
#pragma unroll
      for (int m = 0; m < 4; ++m)
        af[m] = *(const s16x8*)(As + (wr + m * 16 + l16) * LDP + ks * 32 + lg * 8);
#pragma unroll
      for (int n = 0; n < 4; ++n)
        bq[n] = *(const s16x8*)(Bs + (wc + n * 16 + l16) * LDP + ks * 32 + lg * 8);
#pragma unroll
      for (int m = 0; m < 4; ++m)
#pragma unroll
        for (int n = 0; n < 4; ++n)
          acc[m][n] = __builtin_amdgcn_mfma_f32_16x16x32_bf16(af[m], bq[n], acc[m][n], 0, 0, 0);
    }
  }

  const int colbase = bn + wc;   // 64-aligned -> exactly one head-dim slab
  if (colbase < 2 * DMODEL) {
    // q/k: fused EDM2 norm (+1/8 attn scale for q), write bf16
    const float qmul = (colbase < DMODEL) ? 0.125f : 1.0f;
#pragma unroll
    for (int m = 0; m < 4; ++m)
#pragma unroll
      for (int r = 0; r < 4; ++r) {
        float ss = 0.f;
#pragma unroll
        for (int n = 0; n < 4; ++n) ss += acc[m][n][r] * acc[m][n][r];
        ss += __shfl_xor(ss, 1); ss += __shfl_xor(ss, 2);
        ss += __shfl_xor(ss, 4); ss += __shfl_xor(ss, 8);
        const float scale = qmul / (1e-4f + sqrtf(ss) * 0.125f);
#pragma unroll
        for (int n = 0; n < 4; ++n)
          C[(size_t)(bm + wr + m * 16 + lg * 4 + r) * N + (colbase + n * 16 + l16)] =
              f2bf(acc[m][n][r] * scale);
      }
  } else {
    // v: write transposed to Vt[bh][d][t]
    const int hv = (colbase - 2 * DMODEL) >> 6;
    const int token0 = bm + wr;
    const int b_ = token0 >> 11;
    const int bh = b_ * NHEAD + hv;
    const int t0 = (token0 & (SEQ - 1)) + lg * 4;
#pragma unroll
    for (int m = 0; m < 4; ++m)
#pragma unroll
      for (int n = 0; n < 4; ++n) {
        const int d = n * 16 + l16;
        s16x4 ov = { (short)f2bf(acc[m][n][0]), (short)f2bf(acc[m][n][1]),
                     (short)f2bf(acc[m][n][2]), (short)f2bf(acc[m][n][3]) };
        *(s16x4*)(Vt + (size_t)(bh * HDIM + d) * SEQ + t0 + m * 16) = ov;
      }
  }
}

// ---------------------------------------------------------------------------
// 2b) out GEMM — R14/R16 winner, f32 output
// ---------------------------------------------------------------------------
__global__ __launch_bounds__(256, 3) void k_gemm_out(const unsigned short* __restrict__ A,
                                                     const unsigned short* __restrict__ Bm,
                                                     float* __restrict__ C,
                                                     int M, int N, int K) {
  __shared__ unsigned short As[128 * LDP];
  __shared__ unsigned short Bs[128 * LDP];
  const int tid = threadIdx.x;
  const int nbn = N >> 7;
  const int bm = (blockIdx.x / nbn) << 7;
  const int bn = (blockIdx.x % nbn) << 7;
  const int wave = tid >> 6, lane = tid & 63;
  const int wr = (wave >> 1) << 6, wc = (wave & 1) << 6;
  const int l16 = lane & 15, lg = lane >> 4;

  f32x4 acc[4][4];
#pragma unroll
  for (int m = 0; m < 4; ++m)
#pragma unroll
    for (int n = 0; n < 4; ++n) acc[m][n] = (f32x4){0.f, 0.f, 0.f, 0.f};

  s16x8 ra[4], rb[4];
#pragma unroll
  for (int it = 0; it < 4; ++it) {
    const int c = it * 256 + tid;
    const int r = c >> 3, col = (c & 7) << 3;
    ra[it] = *(const s16x8*)(A + (size_t)(bm + r) * K + col);
    rb[it] = *(const s16x8*)(Bm + (size_t)(bn + r) * K + col);
  }

  for (int k0 = 0; k0 < K; k0 += 64) {
    __syncthreads();
#pragma unroll
    for (int it = 0; it < 4; ++it) {
      const int c = it * 256 + tid;
      const int r = c >> 3, col = (c & 7) << 3;
      *(s16x8*)(As + r * LDP + col) = ra[it];
      *(s16x8*)(Bs + r * LDP + col) = rb[it];
    }
    __syncthreads();
    if (k0 + 64 < K) {
#pragma unroll
      for (int it = 0; it < 4; ++it) {
        const int c = it * 256 + tid;
        const int r = c >> 3, col = (c & 7) << 3;
        ra[it] = *(const s16x8*)(A + (size_t)(bm + r) * K + k0 + 64 + col);
        rb[it] = *(const s16x8*)(Bm + (size_t)(bn + r) * K + k0 + 64 + col);
      }
    }
#pragma unroll
    for (int ks = 0; ks < 2; ++ks) {
      s16x8 af[4], bq[4];
#pragma unroll
      for (int m = 0; m < 4; ++m)
        af[m] = *(const s16x8*)(As + (wr + m * 16 + l16) * LDP + ks * 32 + lg * 8);
#pragma unroll
      for (int n = 0; n < 4; ++n)
        bq[n] = *(const s16x8*)(Bs + (wc + n * 16 + l16) * LDP + ks * 32 + lg * 8);
#pragma unroll
      for (int m = 0; m < 4; ++m)
#pragma unroll
        for (int n = 0; n < 4; ++n)
          acc[m][n] = __builtin_amdgcn_mfma_f32_16x16x32_bf16(af[m], bq[n], acc[m][n], 0, 0, 0);
    }
  }
#pragma unroll
  for (int m = 0; m < 4; ++m)
#pragma unroll
    for (int n = 0; n < 4; ++n)
#pragma unroll
      for (int r = 0; r < 4; ++r)
        C[(size_t)(bm + wr + m * 16 + lg * 4 + r) * N + (bn + wc + n * 16 + l16)] =
            acc[m][n][r];
}

// ---------------------------------------------------------------------------
// 3) flash attention — R15/R16 CHAMPION, byte-identical. Key-split x2 at
//    128 queries / 8 waves (proven optimum), LDS-staged K/V (coalesced +
//    XOR swizzle), fixed-max softmax __expf(st-8), in-register repack.
// ---------------------------------------------------------------------------
__global__ __launch_bounds__(512) void k_attn(const unsigned short* __restrict__ qkv,
                                              const unsigned short* __restrict__ Vt,
                                              unsigned short* __restrict__ O) {
  const int bid = blockIdx.x;
  const int logical = ((bid & 7) << 6) + (bid >> 3);   // XCD clustering (512%8==0)
  const int bh = logical >> 4, qt = logical & 15;
  const int b = bh >> 4, h = bh & 15;
  const int tid = threadIdx.x;
  const int wave = tid >> 6, lane = tid & 63;
  const int l31 = lane & 31, hi = lane >> 5;
  const int qw = wave & 3, half = wave >> 2;
  const int q0 = qt * 128 + qw * 32;

  __shared__ s16x8 smem[2048];   // [half][K 512 | V 512] staging (32KB); merge alias
  __shared__ float LL[4][64];

  s16x8* ksh = smem + half * 512;
  s16x8* vsh = smem + 1024 + half * 512;

  const unsigned short* qp =
      qkv + (size_t)(b * SEQ + q0 + l31) * QKVC + h * HDIM + hi * 8;
  const s16x8 qf0 = *(const s16x8*)(qp);
  const s16x8 qf1 = *(const s16x8*)(qp + 16);
  const s16x8 qf2 = *(const s16x8*)(qp + 32);
  const s16x8 qf3 = *(const s16x8*)(qp + 48);

  const int t8 = tid & 255;
  const int srow = t8 >> 3, chunk = t8 & 7;
  const unsigned short* ksrc =
      qkv + (size_t)(b * SEQ + half * 1024 + srow) * QKVC + DMODEL + h * HDIM + chunk * 8;
  const unsigned short* vsrc =
      Vt + (size_t)(bh * HDIM + srow) * SEQ + half * 1024 + chunk * 8;
  const int wsl = srow * 8 + (chunk ^ (srow & 7));
  const int wsh = wsl + 256;

  f32x16 acc0 = {0,0,0,0,0,0,0,0,0,0,0,0,0,0,0,0};
  f32x16 acc1 = {0,0,0,0,0,0,0,0,0,0,0,0,0,0,0,0};
  float l = 0.f;

  for (int kt = 0; kt < 1024; kt += 64) {
    const s16x8 rk0 = *(const s16x8*)(ksrc + (size_t)kt * QKVC);
    const s16x8 rk1 = *(const s16x8*)(ksrc + (size_t)(kt + 32) * QKVC);
    const s16x8 rv0 = *(const s16x8*)(vsrc + kt);
    const s16x8 rv1 = *(const s16x8*)(vsrc + (size_t)32 * SEQ + kt);
    __syncthreads();
    ksh[wsl] = rk0; ksh[wsh] = rk1;
    vsh[wsl] = rv0; vsh[wsh] = rv1;
    __syncthreads();
#pragma unroll
    for (int kh = 0; kh < 2; ++kh) {
      const int key = kh * 32 + l31;
      const int kb = key * 8, kx = key & 7;
      f32x16 st = {0,0,0,0,0,0,0,0,0,0,0,0,0,0,0,0};
      st = __builtin_amdgcn_mfma_f32_32x32x16_bf16(ksh[kb + ((0 + hi) ^ kx)], qf0, st, 0, 0, 0);
      st = __builtin_amdgcn_mfma_f32_32x32x16_bf16(ksh[kb + ((2 + hi) ^ kx)], qf1, st, 0, 0, 0);
      st = __builtin_amdgcn_mfma_f32_32x32x16_bf16(ksh[kb + ((4 + hi) ^ kx)], qf2, st, 0, 0, 0);
      st = __builtin_amdgcn_mfma_f32_32x32x16_bf16(ksh[kb + ((6 + hi) ^ kx)], qf3, st, 0, 0, 0);

#pragma unroll
      for (int r = 0; r < 16; ++r) st[r] = __expf(st[r] - 8.f);

      float s0 = (st[0] + st[1]) + (st[2] + st[3]);
      float s1 = (st[4] + st[5]) + (st[6] + st[7]);
      float s2 = (st[8] + st[9]) + (st[10] + st[11]);
      float s3 = (st[12] + st[13]) + (st[14] + st[15]);
      l += (s0 + s1) + (s2 + s3);

      unsigned P0 = pkbf(st[0], st[1]),   P1 = pkbf(st[2], st[3]);
      unsigned P2 = pkbf(st[4], st[5]),   P3 = pkbf(st[6], st[7]);
      unsigned P4 = pkbf(st[8], st[9]),   P5 = pkbf(st[10], st[11]);
      unsigned P6 = pkbf(st[12], st[13]), P7 = pkbf(st[14], st[15]);
      swp(P0, P2);
      swp(P1, P3);
      swp(P4, P6);
      swp(P5, P7);
      u32x4 w0; w0[0] = P0; w0[1] = P1; w0[2] = P2; w0[3] = P3;
      u32x4 w1; w1[0] = P4; w1[1] = P5; w1[2] = P6; w1[3] = P7;
      const s16x8 pf0 = __builtin_bit_cast(s16x8, w0);
      const s16x8 pf1 = __builtin_bit_cast(s16x8, w1);

      const int vb0 = l31 * 8,        vx0 = l31 & 7;
      const int vb1 = (l31 + 32) * 8, vx1 = vx0;
      acc0 = __builtin_amdgcn_mfma_f32_32x32x16_bf16(vsh[vb0 + ((kh * 4 + 0 + hi) ^ vx0)], pf0, acc0, 0, 0, 0);
      acc0 = __builtin_amdgcn_mfma_f32_32x32x16_bf16(vsh[vb0 + ((kh * 4 + 2 + hi) ^ vx0)], pf1, acc0, 0, 0, 0);
      acc1 = __builtin_amdgcn_mfma_f32_32x32x16_bf16(vsh[vb1 + ((kh * 4 + 0 + hi) ^ vx1)], pf0, acc1, 0, 0, 0);
      acc1 = __builtin_amdgcn_mfma_f32_32x32x16_bf16(vsh[vb1 + ((kh * 4 + 2 + hi) ^ vx1)], pf1, acc1, 0, 0, 0);
    }
  }

  l += __shfl_xor(l, 32);

  __syncthreads();
  float* OO = (float*)smem;
  if (half) {
    float* o_ = OO + qw * 2048;
#pragma unroll
    for (int r = 0; r < 16; ++r) {
      o_[r * 64 + lane] = acc0[r];
      o_[(16 + r) * 64 + lane] = acc1[r];
    }
    LL[qw][lane] = l;
  }
  __syncthreads();
  if (!half) {
    const float inv = 1.f / (l + LL[qw][lane]);
    const float* o_ = OO + qw * 2048;
    unsigned short* ob = O + (size_t)(b * SEQ + q0 + l31) * DMODEL + h * HDIM;
#pragma unroll
    for (int g = 0; g < 4; ++g) {
      float e00 = (acc0[4 * g]     + o_[(4 * g) * 64 + lane])     * inv;
      float e01 = (acc0[4 * g + 1] + o_[(4 * g + 1) * 64 + lane]) * inv;
      float e02 = (acc0[4 * g + 2] + o_[(4 * g + 2) * 64 + lane]) * inv;
      float e03 = (acc0[4 * g + 3] + o_[(4 * g + 3) * 64 + lane]) * inv;
      float e10 = (acc1[4 * g]     + o_[(16 + 4 * g) * 64 + lane])     * inv;
      float e11 = (acc1[4 * g + 1] + o_[(16 + 4 * g + 1) * 64 + lane]) * inv;
      float e12 = (acc1[4 * g + 2] + o_[(16 + 4 * g + 2) * 64 + lane]) * inv;
      float e13 = (acc1[4 * g + 3] + o_[(16 + 4 * g + 3) * 64 + lane]) * inv;
      s16x4 o0 = { (short)f2bf(e00), (short)f2bf(e01), (short)f2bf(e02), (short)f2bf(e03) };
      s16x4 o1 = { (short)f2bf(e10), (short)f2bf(e11), (short)f2bf(e12), (short)f2bf(e13) };
      *(s16x4*)(ob + g * 8 + hi * 4) = o0;
      *(s16x4*)(ob + 32 + g * 8 + hi * 4) = o1;
    }
  }
}

// ---------------------------------------------------------------------------
// launch: ws layout (bytes): Wq[0,6M) Wo[6M,8M) Xb[8M,16M) QKV[16M,40M) Vt[40M,48M)
// ---------------------------------------------------------------------------
extern "C" void kernel_launch(void* const* d_in, const int* in_sizes, int n_in,
                              void* d_out, int out_size, void* d_ws, size_t ws_size,
                              hipStream_t stream) {
  const float* x    = (const float*)d_in[0];
  const float* wqkv = (const float*)d_in[1];
  const float* wout = (const float*)d_in[2];
  char* ws = (char*)d_ws;
  unsigned short* Wq  = (unsigned short*)(ws);
  unsigned short* Wo  = (unsigned short*)(ws + 6291456);
  unsigned short* Xb  = (unsigned short*)(ws + 8388608);
  unsigned short* QKV = (unsigned short*)(ws + 16777216);
  unsigned short* Vt  = (unsigned short*)(ws + 41943040);
  (void)in_sizes; (void)n_in; (void)out_size; (void)ws_size;

  k_prep<<<QKVC + DMODEL + NROWS, 256, 0, stream>>>(wqkv, wout, x, Wq, Wo, Xb);
  k_gemm_qkv<<<(NROWS / 128) * (QKVC / 128), 256, 0, stream>>>(Xb, Wq, QKV, Vt);
  k_attn<<<BATCH * NHEAD * 16, 512, 0, stream>>>(QKV, Vt, Xb);
  k_gemm_out<<<(NROWS / 128) * (DMODEL / 128), 256, 0, stream>>>(
      Xb, Wo, (float*)d_out, NROWS, DMODEL, DMODEL);
}